// Round 10
// baseline (375.480 us; speedup 1.0000x reference)
//
#include <hip/hip_runtime.h>
#include <hip/hip_bf16.h>
#include <math.h>

// Problem constants (fixed by the reference).
#define Bn 4
#define Sn 2048
#define En 1024
#define Hn 16
#define Dn 64
#define Mn (Bn * Sn)  // 8192 rows in the flattened GEMMs

typedef __attribute__((ext_vector_type(8))) short short8;
typedef __attribute__((ext_vector_type(4))) short short4v;
typedef __attribute__((ext_vector_type(4))) float f32x4;
typedef __attribute__((ext_vector_type(16))) float f32x16;
typedef __attribute__((ext_vector_type(2))) unsigned int uint2v;

#if __has_builtin(__builtin_amdgcn_exp2f)
#define EXP2(x) __builtin_amdgcn_exp2f(x)
#else
#define EXP2(x) exp2f(x)
#endif

#if __has_builtin(__builtin_amdgcn_permlane32_swap)
#define HAVE_PLSWAP 1
#endif

// async global->LDS, 16 B per lane; LDS dest = wave-uniform base + lane*16
#define GLOAD16(g, s) __builtin_amdgcn_global_load_lds( \
    (const __attribute__((address_space(1))) unsigned int*)(g), \
    (__attribute__((address_space(3))) unsigned int*)(s), 16, 0, 0)

__device__ inline unsigned short f2bf(float f) {  // round-to-nearest-even bf16
    unsigned int u = __float_as_uint(f);
    u += 0x7FFFu + ((u >> 16) & 1u);
    return (unsigned short)(u >> 16);
}
__device__ inline float bf2f(unsigned short h) {
    return __uint_as_float(((unsigned int)h) << 16);
}
__device__ inline short8 ld8s(const unsigned short* p) {  // LDS, 8B-aligned
    union { short4v h[2]; short8 v; } r;
    r.h[0] = *(const short4v*)p;
    r.h[1] = *(const short4v*)(p + 4);
    return r.v;
}
__device__ inline short8 g8(const unsigned short* p) {  // global, 16B-aligned
    union { int4 i; short8 v; } r;
    r.i = *(const int4*)p;
    return r.v;
}

// XOR-swizzled 64x64 bf16 LDS tile helpers (attn): row stride 128 B, byte
// offset XORed with (row&7)<<4. 16B-aligned -> single ds_*_b128 per access.
// (SQ_LDS_BANK_CONFLICT = exactly 4 per b128 read on this pattern --
// structural, scales exactly with read count across r2-r8.)
__device__ inline void st16(unsigned short* base, int row, int col16, int4 v) {
    const unsigned off = ((unsigned)(row * 128 + col16 * 2)) ^ ((unsigned)((row & 7) << 4));
    *(int4*)((char*)base + off) = v;
}
__device__ inline short8 ld16(const unsigned short* base, int row, int col16) {
    const unsigned off = ((unsigned)(row * 128 + col16 * 2)) ^ ((unsigned)((row & 7) << 4));
    union { int4 i; short8 v; } r;
    r.i = *(const int4*)((const char*)base + off);
    return r.v;
}

// ---------------------------------------------------------------------------
// X fp32 -> bf16 (hi only). 4 elts/thread.
// ---------------------------------------------------------------------------
__global__ __launch_bounds__(256) void convx_kernel(
    const float* __restrict__ X, unsigned short* __restrict__ Xh) {
    int i = blockIdx.x * 256 + threadIdx.x;
    float4 v = ((const float4*)X)[i];
    float f[4] = {v.x, v.y, v.z, v.w};
    short4v h;
#pragma unroll
    for (int j = 0; j < 4; ++j) h[j] = (short)f2bf(f[j]);
    ((short4v*)Xh)[i] = h;
}

// ---------------------------------------------------------------------------
// z=0..2: Wq/Wk/Wv fp32 [K][N] -> transposed bf16 WqkvT + z*WN (rowLen 1024)
// z=3:    Wo -> WoT (rowLen 1024)
// z=4:    RoPE cos/sin table, fp64-accurate: [S][32] each (fused launch).
// ---------------------------------------------------------------------------
__global__ __launch_bounds__(256) void tconv5_kernel(
    const float* __restrict__ Wq, const float* __restrict__ Wk,
    const float* __restrict__ Wv, const float* __restrict__ Wo,
    unsigned short* __restrict__ WqkvT, unsigned short* __restrict__ WoT,
    float* __restrict__ ct, float* __restrict__ st) {
    const int m = blockIdx.z;
    if (m == 4) {  // RoPE table: 256 blocks x 256 threads = Sn*32 entries
        const int i = (blockIdx.y * 16 + blockIdx.x) * 256 + threadIdx.x;
        const int s = i >> 5, p = i & 31;
        double inv = pow(10000.0, -(double)p / 32.0);
        double a = (double)s * inv;
        ct[i] = (float)cos(a);
        st[i] = (float)sin(a);
        return;
    }
    const float* W = (m == 0) ? Wq : (m == 1) ? Wk : (m == 2) ? Wv : Wo;
    unsigned short* dst = (m < 3) ? WqkvT + (size_t)m * En * En : WoT;

    __shared__ float Ws[64][65];
    const int t = threadIdx.x;
    const int kb = blockIdx.y * 64, nb = blockIdx.x * 64;
    const int lr = t >> 2, lc = (t & 3) * 16;
#pragma unroll
    for (int u = 0; u < 4; ++u) {
        float4 v = *(const float4*)&W[(size_t)(kb + lr) * En + nb + lc + 4 * u];
        Ws[lr][lc + 4 * u + 0] = v.x; Ws[lr][lc + 4 * u + 1] = v.y;
        Ws[lr][lc + 4 * u + 2] = v.z; Ws[lr][lc + 4 * u + 3] = v.w;
    }
    __syncthreads();
    const int orow = t >> 2, ock = (t & 3) * 16;
#pragma unroll
    for (int u = 0; u < 4; ++u) {
        short4v hs;
#pragma unroll
        for (int j = 0; j < 4; ++j) hs[j] = (short)f2bf(Ws[ock + 4 * u + j][orow]);
        *(short4v*)&dst[(size_t)(nb + orow) * En + kb + ock + 4 * u] = hs;
    }
}

// ---------------------------------------------------------------------------
// m97-recipe MFMA GEMM (reverted to the r7-verified structure; the r9
// 2-phase 256x128 experiment regressed: 5 barriers/K-tile at 1 block/CU ->
// MfmaUtil 16.9 AND VALUBusy 12.8, both pipes idle).
// C[M][N] = A[M][KN] . Bt[N][KN]^T. 128x128 tile, 4 waves, each 64x64 as
// 4x4 of 16x16x32 bf16 MFMA. Staging via global_load_lds width=16 into
// UNPADDED As/Bs[128][64]. Per K-iter: 8 global_load_lds + 16 ds_read_b128
// + 32 MFMA per wave, 2 barriers. T1 XCD swizzle kept (neutral, harmless).
// C/D (16x16): col = lane&15, row = (lane>>4)*4 + reg.
// EPI 0: fp32 out [M][En] + bias b0   (final projection)
// EPI 1: fused QKV epilogue; matrix by n0>>10:
//   mat 0/1 (Q/K): RoPE (+Q scale), bf16 out [B,H,S,D].
//   mat 2 (V): NEW fused transpose -> writes VbT[B,H,D,S] directly via an
//     LDS [128][136] bf16 tile (reuses the staging LDS after the K-loop;
//     136-short stride: 16B-aligned rows, 4-bank rotation, <=2-way conflict).
//     Values bit-identical to the old vtrans path (f2bf(acc+bias) both ways);
//     deletes the separate vtrans kernel + one launch gap.
// ---------------------------------------------------------------------------
template <int KN, int EPI>
__global__ __launch_bounds__(256) void gemm97(
    const unsigned short* __restrict__ A, const unsigned short* __restrict__ Bt,
    const float* __restrict__ b0, const float* __restrict__ bkv,
    const float* __restrict__ bvv,
    unsigned short* __restrict__ oQ, unsigned short* __restrict__ oK,
    unsigned short* __restrict__ oV, float* __restrict__ oF,
    const float* __restrict__ ct, const float* __restrict__ st) {
    // 34816 B: As[128][64] | Bs[128][64] staging, reused as T[128][136] by
    // the V-transpose epilogue.
    __shared__ __align__(16) unsigned short shmem[17408];
    unsigned short (*As)[64] = (unsigned short(*)[64])&shmem[0];
    unsigned short (*Bs)[64] = (unsigned short(*)[64])&shmem[8192];
    const int t = threadIdx.x;
    const int w = t >> 6, l = t & 63;
    const int wm = w & 1, wn = w >> 1;
    const int q = l >> 4, ln16 = l & 15;  // quad, lane-in-16
    const int r8 = l >> 3, i8 = l & 7;    // staging: row-in-8, 16B chunk

    // T1: XCD-aware swizzle -- each XCD gets a contiguous chunk of work-ids.
    int bx = blockIdx.x, by = blockIdx.y;
    {
        const int gx = gridDim.x;
        const int nwg = gx * gridDim.y;
        if ((nwg & 7) == 0) {
            const int n = by * gx + bx;
            const int s = (n & 7) * (nwg >> 3) + (n >> 3);
            bx = s % gx; by = s / gx;
        }
    }
    const int m0 = by * 128, n0 = bx * 128;

    f32x4 acc[4][4];
#pragma unroll
    for (int i = 0; i < 4; ++i)
#pragma unroll
        for (int j = 0; j < 4; ++j)
#pragma unroll
            for (int r = 0; r < 4; ++r) acc[i][j][r] = 0.0f;

    // wave w stages rows 32w..32w+31 of both tiles; lane -> (8j+r8, 8*i8)
    const unsigned short* Ag = &A[(size_t)(m0 + 32 * w + r8) * KN + 8 * i8];
    const unsigned short* Bg = &Bt[(size_t)(n0 + 32 * w + r8) * KN + 8 * i8];

    for (int k0 = 0; k0 < KN; k0 += 64) {
        __syncthreads();  // prev iter's ds_reads done before overwrite
#pragma unroll
        for (int j = 0; j < 4; ++j) {
            GLOAD16(Ag + (size_t)(8 * j) * KN + k0, &As[32 * w + 8 * j][0]);
            GLOAD16(Bg + (size_t)(8 * j) * KN + k0, &Bs[32 * w + 8 * j][0]);
        }
        __syncthreads();  // compiler drains vmcnt before this barrier
#pragma unroll
        for (int ks = 0; ks < 2; ++ks) {
            short8 af[4], bf[4];
#pragma unroll
            for (int i = 0; i < 4; ++i)
                af[i] = ld8s(&As[64 * wm + 16 * i + ln16][32 * ks + 8 * q]);
#pragma unroll
            for (int j = 0; j < 4; ++j)
                bf[j] = ld8s(&Bs[64 * wn + 16 * j + ln16][32 * ks + 8 * q]);
#pragma unroll
            for (int i = 0; i < 4; ++i)
#pragma unroll
                for (int j = 0; j < 4; ++j)
                    acc[i][j] = __builtin_amdgcn_mfma_f32_16x16x32_bf16(
                        af[i], bf[j], acc[i][j], 0, 0, 0);
        }
    }

    if (EPI == 0) {
#pragma unroll
        for (int i = 0; i < 4; ++i)
#pragma unroll
            for (int r = 0; r < 4; ++r) {
                const int m = m0 + 64 * wm + 16 * i + 4 * q + r;
#pragma unroll
                for (int j = 0; j < 4; ++j) {
                    const int n = n0 + 64 * wn + 16 * j + ln16;
                    oF[(size_t)m * En + n] = acc[i][j][r] + b0[n];
                }
            }
    } else {
        const int mat = n0 >> 10;               // 0=Q, 1=K, 2=V (block-uniform)
        const int nIn0 = n0 & 1023;             // 128-aligned col in matrix
        if (mat == 2) {
            // ---- fused V transpose: acc -> T[d_local][s_local] -> VbT ----
            const int bb = m0 >> 11, s0 = m0 & (Sn - 1);
            __syncthreads();  // all waves' K-loop ds_reads consumed
#pragma unroll
            for (int i = 0; i < 4; ++i)
#pragma unroll
                for (int j = 0; j < 4; ++j) {
                    const int dl = 64 * wn + 16 * j + ln16;
                    const float bv2 = bvv[nIn0 + dl];
#pragma unroll
                    for (int r = 0; r < 4; ++r) {
                        const int sl = 64 * wm + 16 * i + 4 * q + r;
                        shmem[dl * 136 + sl] = f2bf(acc[i][j][r] + bv2);
                    }
                }
            __syncthreads();
            // write-out: thread t owns d-row t>>1, s-half (t&1)*64 (128B)
            const int dr2 = t >> 1, sc2 = (t & 1) * 64;
            const int hh2 = (nIn0 >> 6) + (dr2 >> 6);
            unsigned short* vp =
                &oV[(((size_t)(bb * Hn + hh2)) * Dn + (dr2 & 63)) * Sn + s0 + sc2];
            const unsigned short* tp = &shmem[dr2 * 136 + sc2];
#pragma unroll
            for (int u = 0; u < 8; ++u)
                *(int4*)(vp + 8 * u) = *(const int4*)(tp + 8 * u);
        } else {
            const int nIn = nIn0 + 64 * wn;     // 64-aligned col in matrix
            const int hh = nIn >> 6;            // head
            const float* bias = (mat == 0) ? b0 : bkv;
            unsigned short* op = (mat == 0) ? oQ : oK;
#pragma unroll
            for (int i = 0; i < 4; ++i)
#pragma unroll
                for (int r = 0; r < 4; ++r) {
                    const int m = m0 + 64 * wm + 16 * i + 4 * q + r;
                    const int b = m >> 11, s2 = m & (Sn - 1);
                    const size_t base = (((size_t)(b * Hn + hh)) * Sn + s2) * Dn;
#pragma unroll
                    for (int j = 0; j < 2; ++j) {  // RoPE pairs: tiles j, j+2
                        const int nh = 16 * j + ln16;  // 0..31 == freq idx
                        float v0 = acc[i][j][r] + bias[nIn + nh];
                        float v1 = acc[i][j + 2][r] + bias[nIn + nh + 32];
                        float c = ct[s2 * 32 + nh], sn = st[s2 * 32 + nh];
                        float o0 = v0 * c - v1 * sn;
                        float o1 = v1 * c + v0 * sn;
                        if (mat == 0) {
                            o0 *= 0.18033688011112042f;  // D^-0.5 * log2(e)
                            o1 *= 0.18033688011112042f;
                        }
                        op[base + nh] = f2bf(o0);
                        op[base + nh + 32] = f2bf(o1);
                    }
                }
        }
    }
}

// ---------------------------------------------------------------------------
// Attn softmax helpers (round-3-verified formulation: truncate-to-bf16 pack,
// lsum accumulates the truncated values so numerator == denominator terms).
// ---------------------------------------------------------------------------
__device__ inline void softpack(const f32x16& accS, unsigned long long bm,
                                int c, int h2, float* lsum, unsigned* pw) {
#pragma unroll
    for (int g = 0; g < 4; ++g)
#pragma unroll
        for (int j = 0; j < 2; ++j) {
            const int r0 = 4 * g + 2 * j;
            float p0 = EXP2(accS[r0]);
            float p1 = EXP2(accS[r0 + 1]);
            if (bm) {  // wave-uniform; all-false mask skips this
                const int key = 32 * c + 8 * g + 4 * h2 + 2 * j;
                if ((bm >> key) & 1) p0 = 0.0f;
                if ((bm >> (key + 1)) & 1) p1 = 0.0f;
            }
            const unsigned u0 = __float_as_uint(p0) & 0xFFFF0000u;
            const unsigned u1 = __float_as_uint(p1) & 0xFFFF0000u;
            lsum[g] += __uint_as_float(u0);
            lsum[g] += __uint_as_float(u1);
            pw[2 * g + j] = (u0 >> 16) | u1;
        }
}

__device__ inline short8 pv_afrag(const unsigned* pw, int s, int h2) {
    union { unsigned u[4]; short8 v; } af;
#ifdef HAVE_PLSWAP
    uint2v r02 = __builtin_amdgcn_permlane32_swap(
        pw[4 * s + 0], pw[4 * s + 2], false, false);
    uint2v r13 = __builtin_amdgcn_permlane32_swap(
        pw[4 * s + 1], pw[4 * s + 3], false, false);
    af.u[0] = r02[0]; af.u[1] = r13[0];
    af.u[2] = r02[1]; af.u[3] = r13[1];
#else
    const unsigned x0 = pw[4 * s + 0], x1 = pw[4 * s + 1];
    const unsigned y0 = pw[4 * s + 2], y1 = pw[4 * s + 3];
    const unsigned py0 = (unsigned)__shfl_xor((int)y0, 32);
    const unsigned py1 = (unsigned)__shfl_xor((int)y1, 32);
    const unsigned px0 = (unsigned)__shfl_xor((int)x0, 32);
    const unsigned px1 = (unsigned)__shfl_xor((int)x1, 32);
    af.u[0] = h2 ? py0 : x0;
    af.u[1] = h2 ? py1 : x1;
    af.u[2] = h2 ? y0 : px0;
    af.u[3] = h2 ? y1 : px1;
#endif
    return af.v;
}

// ---------------------------------------------------------------------------
// MFMA flash attention, swapped-QK^T (round-7 configuration EXACT -- best
// measured: 117.8 µs, VGPR 128).
//   S^T = mfma(K, Q): per lane col = q = ln, rows = 16 keys.
//   P packed in-register (truncate-bf16) + v_permlane32_swap half-wave
//   exchange. KVBLK=64, 1 barrier per tile, XOR-swizzled K/V LDS tiles.
// O written HI-ONLY bf16 into Obuf[Mn][1024] ([S,H,D] cols; r7-verified:
// absmax unchanged at 2.44e-4).
// ---------------------------------------------------------------------------
__global__ __launch_bounds__(256) void attn_mfma_kernel(
    const unsigned short* __restrict__ Qb, const unsigned short* __restrict__ Kb,
    const unsigned short* __restrict__ VbT, const unsigned char* __restrict__ mask,
    unsigned short* __restrict__ Obuf) {
    __shared__ __align__(16) unsigned short Ks[2][64][64];  // [key][d], swizzled
    __shared__ __align__(16) unsigned short Vs[2][64][64];  // [d][key], swizzled

    const int t = threadIdx.x;
    const int w = t >> 6, l = t & 63, h2 = l >> 5, ln = l & 31;
    const int q0 = blockIdx.x * 128;
    const int h = blockIdx.y, b = blockIdx.z;
    const size_t ho = ((size_t)(b * Hn + h)) * Sn * Dn;
    const unsigned char* maskB = mask + (size_t)b * Sn;

    // Q fragment (B operand): lane holds Q[q0+32w+ln][16s+8h2 .. +7]
    short8 qh[4];
    const int qrow = q0 + 32 * w + ln;
#pragma unroll
    for (int s = 0; s < 4; ++s)
        qh[s] = g8(&Qb[ho + (size_t)qrow * Dn + 16 * s + 8 * h2]);

    f32x16 accO0, accO1;
#pragma unroll
    for (int i = 0; i < 16; ++i) { accO0[i] = 0.0f; accO1[i] = 0.0f; }
    float lsum[4] = {0.0f, 0.0f, 0.0f, 0.0f};  // partial P sums, q=ln

    // staging: thread t owns row t>>2 (key for K, d for V), 32 B at col (t&3)*16
    const int kr = t >> 2, kc = (t & 3) * 16;
    const unsigned short* Kp = &Kb[ho + (size_t)kr * Dn + kc];
    const unsigned short* Vp = &VbT[ho + (size_t)kr * Sn + kc];

    int4 ck0 = *(const int4*)Kp, ck1 = *(const int4*)(Kp + 8);
    int4 cv0 = *(const int4*)Vp, cv1 = *(const int4*)(Vp + 8);
    unsigned char cm = maskB[l];

#pragma unroll 2
    for (int kt = 0; kt < Sn / 64; ++kt) {
        const int pb = kt & 1;
        unsigned short* KsP = &Ks[pb][0][0];
        unsigned short* VsP = &Vs[pb][0][0];
        st16(KsP, kr, kc, ck0); st16(KsP, kr, kc + 8, ck1);
        st16(VsP, kr, kc, cv0); st16(VsP, kr, kc + 8, cv1);
        const unsigned long long bm = __ballot(cm != 0);  // keys kt*64 + 0..63
        __syncthreads();
        const int kn = ((kt + 1) & (Sn / 64 - 1)) * 64;  // prefetch (wraps)
        ck0 = *(const int4*)(Kp + (size_t)kn * Dn);
        ck1 = *(const int4*)(Kp + (size_t)kn * Dn + 8);
        cv0 = *(const int4*)(Vp + kn);
        cv1 = *(const int4*)(Vp + kn + 8);
        cm = maskB[kn + l];

#pragma unroll
        for (int c = 0; c < 2; ++c) {  // two 32-key subtiles
            // K fragment (A operand): lane holds K[32c+ln][16s+8h2 .. +7]
            short8 kf[4];
#pragma unroll
            for (int s = 0; s < 4; ++s)
                kf[s] = ld16(KsP, 32 * c + ln, 16 * s + 8 * h2);
            f32x16 accS;
#pragma unroll
            for (int i = 0; i < 16; ++i) accS[i] = 0.0f;
            __builtin_amdgcn_s_setprio(1);
#pragma unroll
            for (int s = 0; s < 4; ++s)  // S^T: col=q=ln, row=key
                accS = __builtin_amdgcn_mfma_f32_32x32x16_bf16(kf[s], qh[s], accS, 0, 0, 0);
            __builtin_amdgcn_s_setprio(0);

            unsigned pw[8];
            softpack(accS, bm, c, h2, lsum, pw);

#pragma unroll
            for (int s = 0; s < 2; ++s) {
                short8 af = pv_afrag(pw, s, h2);
                short8 vA = ld16(VsP, ln, 32 * c + 16 * s + 8 * h2);
                short8 vB = ld16(VsP, 32 + ln, 32 * c + 16 * s + 8 * h2);
                __builtin_amdgcn_s_setprio(1);
                accO0 = __builtin_amdgcn_mfma_f32_32x32x16_bf16(af, vA, accO0, 0, 0, 0);
                accO1 = __builtin_amdgcn_mfma_f32_32x32x16_bf16(af, vB, accO1, 0, 0, 0);
                __builtin_amdgcn_s_setprio(0);
            }
        }
    }

    // full row sum for q=ln: this lane's 16-key groups + partner half-wave's
    const float lme = (lsum[0] + lsum[1]) + (lsum[2] + lsum[3]);
    const float tot = lme + __shfl_xor(lme, 32);
    const float linv = 1.0f / fmaxf(tot, 1e-37f);
#pragma unroll
    for (int r = 0; r < 16; ++r) {
        const int row = (r & 3) + 8 * (r >> 2) + 4 * h2;  // q row of accO[r]
        const float lr = __shfl(linv, row);               // lane `row` holds it
        const int s = q0 + 32 * w + row;
        const size_t base = ((size_t)b * Sn + s) * 1024 + h * Dn;  // [M][1024]
        Obuf[base + ln] = f2bf(accO0[r] * lr);
        Obuf[base + 32 + ln] = f2bf(accO1[r] * lr);
    }
}

// ---------------------------------------------------------------------------
// Workspace (shorts unless noted):
//   Xh | Qb | Kb | VbT | Obuf(NE) | WqkvT(3*WN) | WoT(WN) | ct st
// (Vb gone: V is written transposed directly by the QKV GEMM epilogue.)
// ---------------------------------------------------------------------------
extern "C" void kernel_launch(void* const* d_in, const int* in_sizes, int n_in,
                              void* d_out, int out_size, void* d_ws, size_t ws_size,
                              hipStream_t stream) {
    const float* x  = (const float*)d_in[0];
    const float* Wq = (const float*)d_in[1];
    const float* bq = (const float*)d_in[2];
    const float* Wk = (const float*)d_in[3];
    const float* bk = (const float*)d_in[4];
    const float* Wv = (const float*)d_in[5];
    const float* bv = (const float*)d_in[6];
    const float* Wo = (const float*)d_in[7];
    const float* bo = (const float*)d_in[8];
    const unsigned char* mask = (const unsigned char*)d_in[9];

    const size_t NE = (size_t)Mn * En;  // 8,388,608
    const size_t WN = (size_t)En * En;  // 1,048,576
    unsigned short* ws = (unsigned short*)d_ws;
    unsigned short* Xh = ws;
    unsigned short* Qb = Xh + NE;
    unsigned short* Kb = Qb + NE;
    unsigned short* VbT = Kb + NE;
    unsigned short* Obuf = VbT + NE;        // NE (hi-only bf16, [S,H,D] cols)
    unsigned short* WqkvT = Obuf + NE;      // 3 * WN
    unsigned short* WoT = WqkvT + 3 * WN;   // WN
    float* ct = (float*)(WoT + WN);
    float* st = ct + (size_t)Sn * 32;

    convx_kernel<<<(int)(NE / 1024), 256, 0, stream>>>(x, Xh);
    tconv5_kernel<<<dim3(16, 16, 5), 256, 0, stream>>>(
        Wq, Wk, Wv, Wo, WqkvT, WoT, ct, st);

    gemm97<En, 1><<<dim3(3 * En / 128, Mn / 128), 256, 0, stream>>>(
        Xh, WqkvT, bq, bk, bv, Qb, Kb, VbT, nullptr, ct, st);

    attn_mfma_kernel<<<dim3(Sn / 128, Hn, Bn), 256, 0, stream>>>(
        Qb, Kb, VbT, mask, Obuf);

    gemm97<En, 0><<<dim3(En / 128, Mn / 128), 256, 0, stream>>>(
        Obuf, WoT, bo, nullptr, nullptr, nullptr, nullptr, nullptr,
        (float*)d_out, ct, st);
}

// Round 11
// 305.694 us; speedup vs baseline: 1.2283x; 1.2283x over previous
//
#include <hip/hip_runtime.h>
#include <hip/hip_bf16.h>
#include <math.h>

// Problem constants (fixed by the reference).
#define Bn 4
#define Sn 2048
#define En 1024
#define Hn 16
#define Dn 64
#define Mn (Bn * Sn)  // 8192 rows in the flattened GEMMs

typedef __attribute__((ext_vector_type(8))) short short8;
typedef __attribute__((ext_vector_type(4))) short short4v;
typedef __attribute__((ext_vector_type(4))) float f32x4;
typedef __attribute__((ext_vector_type(16))) float f32x16;
typedef __attribute__((ext_vector_type(2))) unsigned int uint2v;

#if __has_builtin(__builtin_amdgcn_exp2f)
#define EXP2(x) __builtin_amdgcn_exp2f(x)
#else
#define EXP2(x) exp2f(x)
#endif

#if __has_builtin(__builtin_amdgcn_permlane32_swap)
#define HAVE_PLSWAP 1
#endif

// async global->LDS, 16 B per lane; LDS dest = wave-uniform base + lane*16
#define GLOAD16(g, s) __builtin_amdgcn_global_load_lds( \
    (const __attribute__((address_space(1))) unsigned int*)(g), \
    (__attribute__((address_space(3))) unsigned int*)(s), 16, 0, 0)

__device__ inline unsigned short f2bf(float f) {  // round-to-nearest-even bf16
    unsigned int u = __float_as_uint(f);
    u += 0x7FFFu + ((u >> 16) & 1u);
    return (unsigned short)(u >> 16);
}
__device__ inline float bf2f(unsigned short h) {
    return __uint_as_float(((unsigned int)h) << 16);
}
__device__ inline short8 ld8s(const unsigned short* p) {  // LDS, 8B-aligned
    union { short4v h[2]; short8 v; } r;
    r.h[0] = *(const short4v*)p;
    r.h[1] = *(const short4v*)(p + 4);
    return r.v;
}
__device__ inline short8 g8(const unsigned short* p) {  // global, 16B-aligned
    union { int4 i; short8 v; } r;
    r.i = *(const int4*)p;
    return r.v;
}

// XOR-swizzled 64x64 bf16 LDS tile helpers (attn): row stride 128 B, byte
// offset XORed with (row&7)<<4. 16B-aligned -> single ds_*_b128 per access.
// (SQ_LDS_BANK_CONFLICT = exactly 4 per b128 read on this pattern --
// structural, scales exactly with read count across r2-r8.)
__device__ inline void st16(unsigned short* base, int row, int col16, int4 v) {
    const unsigned off = ((unsigned)(row * 128 + col16 * 2)) ^ ((unsigned)((row & 7) << 4));
    *(int4*)((char*)base + off) = v;
}
__device__ inline short8 ld16(const unsigned short* base, int row, int col16) {
    const unsigned off = ((unsigned)(row * 128 + col16 * 2)) ^ ((unsigned)((row & 7) << 4));
    union { int4 i; short8 v; } r;
    r.i = *(const int4*)((const char*)base + off);
    return r.v;
}

// ---------------------------------------------------------------------------
// X fp32 -> bf16 (hi only). 4 elts/thread.
// ---------------------------------------------------------------------------
__global__ __launch_bounds__(256) void convx_kernel(
    const float* __restrict__ X, unsigned short* __restrict__ Xh) {
    int i = blockIdx.x * 256 + threadIdx.x;
    float4 v = ((const float4*)X)[i];
    float f[4] = {v.x, v.y, v.z, v.w};
    short4v h;
#pragma unroll
    for (int j = 0; j < 4; ++j) h[j] = (short)f2bf(f[j]);
    ((short4v*)Xh)[i] = h;
}

// ---------------------------------------------------------------------------
// z=0..2: Wq/Wk/Wv fp32 [K][N] -> transposed bf16 WqkvT + z*WN (rowLen 1024)
// z=3:    Wo -> WoT (rowLen 1024)
// z=4:    RoPE cos/sin table, fp64-accurate: [S][32] each (fused launch).
// ---------------------------------------------------------------------------
__global__ __launch_bounds__(256) void tconv5_kernel(
    const float* __restrict__ Wq, const float* __restrict__ Wk,
    const float* __restrict__ Wv, const float* __restrict__ Wo,
    unsigned short* __restrict__ WqkvT, unsigned short* __restrict__ WoT,
    float* __restrict__ ct, float* __restrict__ st) {
    const int m = blockIdx.z;
    if (m == 4) {  // RoPE table: 256 blocks x 256 threads = Sn*32 entries
        const int i = (blockIdx.y * 16 + blockIdx.x) * 256 + threadIdx.x;
        const int s = i >> 5, p = i & 31;
        double inv = pow(10000.0, -(double)p / 32.0);
        double a = (double)s * inv;
        ct[i] = (float)cos(a);
        st[i] = (float)sin(a);
        return;
    }
    const float* W = (m == 0) ? Wq : (m == 1) ? Wk : (m == 2) ? Wv : Wo;
    unsigned short* dst = (m < 3) ? WqkvT + (size_t)m * En * En : WoT;

    __shared__ float Ws[64][65];
    const int t = threadIdx.x;
    const int kb = blockIdx.y * 64, nb = blockIdx.x * 64;
    const int lr = t >> 2, lc = (t & 3) * 16;
#pragma unroll
    for (int u = 0; u < 4; ++u) {
        float4 v = *(const float4*)&W[(size_t)(kb + lr) * En + nb + lc + 4 * u];
        Ws[lr][lc + 4 * u + 0] = v.x; Ws[lr][lc + 4 * u + 1] = v.y;
        Ws[lr][lc + 4 * u + 2] = v.z; Ws[lr][lc + 4 * u + 3] = v.w;
    }
    __syncthreads();
    const int orow = t >> 2, ock = (t & 3) * 16;
#pragma unroll
    for (int u = 0; u < 4; ++u) {
        short4v hs;
#pragma unroll
        for (int j = 0; j < 4; ++j) hs[j] = (short)f2bf(Ws[ock + 4 * u + j][orow]);
        *(short4v*)&dst[(size_t)(nb + orow) * En + kb + ock + 4 * u] = hs;
    }
}

// ---------------------------------------------------------------------------
// m97-recipe MFMA GEMM (r7-verified structure) + fused V-transpose epilogue.
// __launch_bounds__(256, 4) pins VGPR <= 128: r10 measured the epilogue
// pushing VGPR to 132, which crosses the m69 occupancy cliff (waves/SIMD
// halve at 128) -> occupancy 20.6%->11%, QKV gemm 147.8 µs. Epilogue-only
// values are dead during the K-loop, so any spill from the cap lands in the
// once-per-block epilogue, not the hot loop.
// C[M][N] = A[M][KN] . Bt[N][KN]^T. 128x128 tile, 4 waves, each 64x64 as
// 4x4 of 16x16x32 bf16 MFMA. global_load_lds width=16 into UNPADDED
// As/Bs[128][64]. Per K-iter: 8 gload + 16 ds_read_b128 + 32 MFMA/wave,
// 2 barriers. T1 XCD swizzle kept. C/D (16x16): col=lane&15, row=(l>>4)*4+r.
// EPI 0: fp32 out [M][En] + bias b0   (final projection)
// EPI 1: fused QKV epilogue; matrix by n0>>10:
//   mat 0/1 (Q/K): RoPE (+Q scale), bf16 out [B,H,S,D].
//   mat 2 (V): fused transpose -> VbT[B,H,D,S] via LDS T[128][136] (reuses
//     staging LDS after the K-loop; 136-short stride: 16B rows, 4-bank
//     rotation, <=2-way conflict). Values bit-identical to old vtrans.
// ---------------------------------------------------------------------------
template <int KN, int EPI>
__global__ __launch_bounds__(256, 4) void gemm97(
    const unsigned short* __restrict__ A, const unsigned short* __restrict__ Bt,
    const float* __restrict__ b0, const float* __restrict__ bkv,
    const float* __restrict__ bvv,
    unsigned short* __restrict__ oQ, unsigned short* __restrict__ oK,
    unsigned short* __restrict__ oV, float* __restrict__ oF,
    const float* __restrict__ ct, const float* __restrict__ st) {
    // 34816 B: As[128][64] | Bs[128][64] staging, reused as T[128][136] by
    // the V-transpose epilogue.
    __shared__ __align__(16) unsigned short shmem[17408];
    unsigned short (*As)[64] = (unsigned short(*)[64])&shmem[0];
    unsigned short (*Bs)[64] = (unsigned short(*)[64])&shmem[8192];
    const int t = threadIdx.x;
    const int w = t >> 6, l = t & 63;
    const int wm = w & 1, wn = w >> 1;
    const int q = l >> 4, ln16 = l & 15;  // quad, lane-in-16
    const int r8 = l >> 3, i8 = l & 7;    // staging: row-in-8, 16B chunk

    // T1: XCD-aware swizzle -- each XCD gets a contiguous chunk of work-ids.
    int bx = blockIdx.x, by = blockIdx.y;
    {
        const int gx = gridDim.x;
        const int nwg = gx * gridDim.y;
        if ((nwg & 7) == 0) {
            const int n = by * gx + bx;
            const int s = (n & 7) * (nwg >> 3) + (n >> 3);
            bx = s % gx; by = s / gx;
        }
    }
    const int m0 = by * 128, n0 = bx * 128;

    f32x4 acc[4][4];
#pragma unroll
    for (int i = 0; i < 4; ++i)
#pragma unroll
        for (int j = 0; j < 4; ++j)
#pragma unroll
            for (int r = 0; r < 4; ++r) acc[i][j][r] = 0.0f;

    // wave w stages rows 32w..32w+31 of both tiles; lane -> (8j+r8, 8*i8)
    const unsigned short* Ag = &A[(size_t)(m0 + 32 * w + r8) * KN + 8 * i8];
    const unsigned short* Bg = &Bt[(size_t)(n0 + 32 * w + r8) * KN + 8 * i8];

    for (int k0 = 0; k0 < KN; k0 += 64) {
        __syncthreads();  // prev iter's ds_reads done before overwrite
#pragma unroll
        for (int j = 0; j < 4; ++j) {
            GLOAD16(Ag + (size_t)(8 * j) * KN + k0, &As[32 * w + 8 * j][0]);
            GLOAD16(Bg + (size_t)(8 * j) * KN + k0, &Bs[32 * w + 8 * j][0]);
        }
        __syncthreads();  // compiler drains vmcnt before this barrier
#pragma unroll
        for (int ks = 0; ks < 2; ++ks) {
            short8 af[4], bf[4];
#pragma unroll
            for (int i = 0; i < 4; ++i)
                af[i] = ld8s(&As[64 * wm + 16 * i + ln16][32 * ks + 8 * q]);
#pragma unroll
            for (int j = 0; j < 4; ++j)
                bf[j] = ld8s(&Bs[64 * wn + 16 * j + ln16][32 * ks + 8 * q]);
#pragma unroll
            for (int i = 0; i < 4; ++i)
#pragma unroll
                for (int j = 0; j < 4; ++j)
                    acc[i][j] = __builtin_amdgcn_mfma_f32_16x16x32_bf16(
                        af[i], bf[j], acc[i][j], 0, 0, 0);
        }
    }

    if (EPI == 0) {
#pragma unroll
        for (int i = 0; i < 4; ++i)
#pragma unroll
            for (int r = 0; r < 4; ++r) {
                const int m = m0 + 64 * wm + 16 * i + 4 * q + r;
#pragma unroll
                for (int j = 0; j < 4; ++j) {
                    const int n = n0 + 64 * wn + 16 * j + ln16;
                    oF[(size_t)m * En + n] = acc[i][j][r] + b0[n];
                }
            }
    } else {
        const int mat = n0 >> 10;               // 0=Q, 1=K, 2=V (block-uniform)
        const int nIn0 = n0 & 1023;             // 128-aligned col in matrix
        if (mat == 2) {
            // ---- fused V transpose: acc -> T[d_local][s_local] -> VbT ----
            __syncthreads();  // all waves' K-loop ds_reads consumed
#pragma unroll
            for (int i = 0; i < 4; ++i)
#pragma unroll
                for (int j = 0; j < 4; ++j) {
                    const int dl = 64 * wn + 16 * j + ln16;
                    const float bv2 = bvv[nIn0 + dl];
#pragma unroll
                    for (int r = 0; r < 4; ++r) {
                        const int sl = 64 * wm + 16 * i + 4 * q + r;
                        shmem[dl * 136 + sl] = f2bf(acc[i][j][r] + bv2);
                    }
                }
            __syncthreads();
            // write-out: thread t owns d-row t>>1, s-half (t&1)*64 (128B)
            const int dr2 = t >> 1, sc2 = (t & 1) * 64;
            const int hh2 = (nIn0 >> 6) + (dr2 >> 6);
            unsigned short* vp =
                &oV[(((size_t)((m0 >> 11) * Hn + hh2)) * Dn + (dr2 & 63)) * Sn
                    + (m0 & (Sn - 1)) + sc2];
            const unsigned short* tp = &shmem[dr2 * 136 + sc2];
#pragma unroll
            for (int u = 0; u < 8; ++u)
                *(int4*)(vp + 8 * u) = *(const int4*)(tp + 8 * u);
        } else {
            const int nIn = nIn0 + 64 * wn;     // 64-aligned col in matrix
            const int hh = nIn >> 6;            // head
            const float* bias = (mat == 0) ? b0 : bkv;
            unsigned short* op = (mat == 0) ? oQ : oK;
#pragma unroll
            for (int i = 0; i < 4; ++i)
#pragma unroll
                for (int r = 0; r < 4; ++r) {
                    const int m = m0 + 64 * wm + 16 * i + 4 * q + r;
                    const int b = m >> 11, s2 = m & (Sn - 1);
                    const size_t base = (((size_t)(b * Hn + hh)) * Sn + s2) * Dn;
#pragma unroll
                    for (int j = 0; j < 2; ++j) {  // RoPE pairs: tiles j, j+2
                        const int nh = 16 * j + ln16;  // 0..31 == freq idx
                        float v0 = acc[i][j][r] + bias[nIn + nh];
                        float v1 = acc[i][j + 2][r] + bias[nIn + nh + 32];
                        float c = ct[s2 * 32 + nh], sn = st[s2 * 32 + nh];
                        float o0 = v0 * c - v1 * sn;
                        float o1 = v1 * c + v0 * sn;
                        if (mat == 0) {
                            o0 *= 0.18033688011112042f;  // D^-0.5 * log2(e)
                            o1 *= 0.18033688011112042f;
                        }
                        op[base + nh] = f2bf(o0);
                        op[base + nh + 32] = f2bf(o1);
                    }
                }
        }
    }
}

// ---------------------------------------------------------------------------
// Attn softmax helpers (round-3-verified formulation: truncate-to-bf16 pack,
// lsum accumulates the truncated values so numerator == denominator terms).
// ---------------------------------------------------------------------------
__device__ inline void softpack(const f32x16& accS, unsigned long long bm,
                                int c, int h2, float* lsum, unsigned* pw) {
#pragma unroll
    for (int g = 0; g < 4; ++g)
#pragma unroll
        for (int j = 0; j < 2; ++j) {
            const int r0 = 4 * g + 2 * j;
            float p0 = EXP2(accS[r0]);
            float p1 = EXP2(accS[r0 + 1]);
            if (bm) {  // wave-uniform; all-false mask skips this
                const int key = 32 * c + 8 * g + 4 * h2 + 2 * j;
                if ((bm >> key) & 1) p0 = 0.0f;
                if ((bm >> (key + 1)) & 1) p1 = 0.0f;
            }
            const unsigned u0 = __float_as_uint(p0) & 0xFFFF0000u;
            const unsigned u1 = __float_as_uint(p1) & 0xFFFF0000u;
            lsum[g] += __uint_as_float(u0);
            lsum[g] += __uint_as_float(u1);
            pw[2 * g + j] = (u0 >> 16) | u1;
        }
}

__device__ inline short8 pv_afrag(const unsigned* pw, int s, int h2) {
    union { unsigned u[4]; short8 v; } af;
#ifdef HAVE_PLSWAP
    uint2v r02 = __builtin_amdgcn_permlane32_swap(
        pw[4 * s + 0], pw[4 * s + 2], false, false);
    uint2v r13 = __builtin_amdgcn_permlane32_swap(
        pw[4 * s + 1], pw[4 * s + 3], false, false);
    af.u[0] = r02[0]; af.u[1] = r13[0];
    af.u[2] = r02[1]; af.u[3] = r13[1];
#else
    const unsigned x0 = pw[4 * s + 0], x1 = pw[4 * s + 1];
    const unsigned y0 = pw[4 * s + 2], y1 = pw[4 * s + 3];
    const unsigned py0 = (unsigned)__shfl_xor((int)y0, 32);
    const unsigned py1 = (unsigned)__shfl_xor((int)y1, 32);
    const unsigned px0 = (unsigned)__shfl_xor((int)x0, 32);
    const unsigned px1 = (unsigned)__shfl_xor((int)x1, 32);
    af.u[0] = h2 ? py0 : x0;
    af.u[1] = h2 ? py1 : x1;
    af.u[2] = h2 ? y0 : px0;
    af.u[3] = h2 ? y1 : px1;
#endif
    return af.v;
}

// ---------------------------------------------------------------------------
// MFMA flash attention, swapped-QK^T (round-7 configuration EXACT -- best
// measured: 117.8 µs, VGPR 128).
//   S^T = mfma(K, Q): per lane col = q = ln, rows = 16 keys.
//   P packed in-register (truncate-bf16) + v_permlane32_swap half-wave
//   exchange. KVBLK=64, 1 barrier per tile, XOR-swizzled K/V LDS tiles.
// O written HI-ONLY bf16 into Obuf[Mn][1024] ([S,H,D] cols; r7-verified:
// absmax unchanged at 2.44e-4).
// ---------------------------------------------------------------------------
__global__ __launch_bounds__(256) void attn_mfma_kernel(
    const unsigned short* __restrict__ Qb, const unsigned short* __restrict__ Kb,
    const unsigned short* __restrict__ VbT, const unsigned char* __restrict__ mask,
    unsigned short* __restrict__ Obuf) {
    __shared__ __align__(16) unsigned short Ks[2][64][64];  // [key][d], swizzled
    __shared__ __align__(16) unsigned short Vs[2][64][64];  // [d][key], swizzled

    const int t = threadIdx.x;
    const int w = t >> 6, l = t & 63, h2 = l >> 5, ln = l & 31;
    const int q0 = blockIdx.x * 128;
    const int h = blockIdx.y, b = blockIdx.z;
    const size_t ho = ((size_t)(b * Hn + h)) * Sn * Dn;
    const unsigned char* maskB = mask + (size_t)b * Sn;

    // Q fragment (B operand): lane holds Q[q0+32w+ln][16s+8h2 .. +7]
    short8 qh[4];
    const int qrow = q0 + 32 * w + ln;
#pragma unroll
    for (int s = 0; s < 4; ++s)
        qh[s] = g8(&Qb[ho + (size_t)qrow * Dn + 16 * s + 8 * h2]);

    f32x16 accO0, accO1;
#pragma unroll
    for (int i = 0; i < 16; ++i) { accO0[i] = 0.0f; accO1[i] = 0.0f; }
    float lsum[4] = {0.0f, 0.0f, 0.0f, 0.0f};  // partial P sums, q=ln

    // staging: thread t owns row t>>2 (key for K, d for V), 32 B at col (t&3)*16
    const int kr = t >> 2, kc = (t & 3) * 16;
    const unsigned short* Kp = &Kb[ho + (size_t)kr * Dn + kc];
    const unsigned short* Vp = &VbT[ho + (size_t)kr * Sn + kc];

    int4 ck0 = *(const int4*)Kp, ck1 = *(const int4*)(Kp + 8);
    int4 cv0 = *(const int4*)Vp, cv1 = *(const int4*)(Vp + 8);
    unsigned char cm = maskB[l];

#pragma unroll 2
    for (int kt = 0; kt < Sn / 64; ++kt) {
        const int pb = kt & 1;
        unsigned short* KsP = &Ks[pb][0][0];
        unsigned short* VsP = &Vs[pb][0][0];
        st16(KsP, kr, kc, ck0); st16(KsP, kr, kc + 8, ck1);
        st16(VsP, kr, kc, cv0); st16(VsP, kr, kc + 8, cv1);
        const unsigned long long bm = __ballot(cm != 0);  // keys kt*64 + 0..63
        __syncthreads();
        const int kn = ((kt + 1) & (Sn / 64 - 1)) * 64;  // prefetch (wraps)
        ck0 = *(const int4*)(Kp + (size_t)kn * Dn);
        ck1 = *(const int4*)(Kp + (size_t)kn * Dn + 8);
        cv0 = *(const int4*)(Vp + kn);
        cv1 = *(const int4*)(Vp + kn + 8);
        cm = maskB[kn + l];

#pragma unroll
        for (int c = 0; c < 2; ++c) {  // two 32-key subtiles
            // K fragment (A operand): lane holds K[32c+ln][16s+8h2 .. +7]
            short8 kf[4];
#pragma unroll
            for (int s = 0; s < 4; ++s)
                kf[s] = ld16(KsP, 32 * c + ln, 16 * s + 8 * h2);
            f32x16 accS;
#pragma unroll
            for (int i = 0; i < 16; ++i) accS[i] = 0.0f;
            __builtin_amdgcn_s_setprio(1);
#pragma unroll
            for (int s = 0; s < 4; ++s)  // S^T: col=q=ln, row=key
                accS = __builtin_amdgcn_mfma_f32_32x32x16_bf16(kf[s], qh[s], accS, 0, 0, 0);
            __builtin_amdgcn_s_setprio(0);

            unsigned pw[8];
            softpack(accS, bm, c, h2, lsum, pw);

#pragma unroll
            for (int s = 0; s < 2; ++s) {
                short8 af = pv_afrag(pw, s, h2);
                short8 vA = ld16(VsP, ln, 32 * c + 16 * s + 8 * h2);
                short8 vB = ld16(VsP, 32 + ln, 32 * c + 16 * s + 8 * h2);
                __builtin_amdgcn_s_setprio(1);
                accO0 = __builtin_amdgcn_mfma_f32_32x32x16_bf16(af, vA, accO0, 0, 0, 0);
                accO1 = __builtin_amdgcn_mfma_f32_32x32x16_bf16(af, vB, accO1, 0, 0, 0);
                __builtin_amdgcn_s_setprio(0);
            }
        }
    }

    // full row sum for q=ln: this lane's 16-key groups + partner half-wave's
    const float lme = (lsum[0] + lsum[1]) + (lsum[2] + lsum[3]);
    const float tot = lme + __shfl_xor(lme, 32);
    const float linv = 1.0f / fmaxf(tot, 1e-37f);
#pragma unroll
    for (int r = 0; r < 16; ++r) {
        const int row = (r & 3) + 8 * (r >> 2) + 4 * h2;  // q row of accO[r]
        const float lr = __shfl(linv, row);               // lane `row` holds it
        const int s = q0 + 32 * w + row;
        const size_t base = ((size_t)b * Sn + s) * 1024 + h * Dn;  // [M][1024]
        Obuf[base + ln] = f2bf(accO0[r] * lr);
        Obuf[base + 32 + ln] = f2bf(accO1[r] * lr);
    }
}

// ---------------------------------------------------------------------------
// Workspace (shorts unless noted):
//   Xh | Qb | Kb | VbT | Obuf(NE) | WqkvT(3*WN) | WoT(WN) | ct st
// (Vb gone: V is written transposed directly by the QKV GEMM epilogue.)
// ---------------------------------------------------------------------------
extern "C" void kernel_launch(void* const* d_in, const int* in_sizes, int n_in,
                              void* d_out, int out_size, void* d_ws, size_t ws_size,
                              hipStream_t stream) {
    const float* x  = (const float*)d_in[0];
    const float* Wq = (const float*)d_in[1];
    const float* bq = (const float*)d_in[2];
    const float* Wk = (const float*)d_in[3];
    const float* bk = (const float*)d_in[4];
    const float* Wv = (const float*)d_in[5];
    const float* bv = (const float*)d_in[6];
    const float* Wo = (const float*)d_in[7];
    const float* bo = (const float*)d_in[8];
    const unsigned char* mask = (const unsigned char*)d_in[9];

    const size_t NE = (size_t)Mn * En;  // 8,388,608
    const size_t WN = (size_t)En * En;  // 1,048,576
    unsigned short* ws = (unsigned short*)d_ws;
    unsigned short* Xh = ws;
    unsigned short* Qb = Xh + NE;
    unsigned short* Kb = Qb + NE;
    unsigned short* VbT = Kb + NE;
    unsigned short* Obuf = VbT + NE;        // NE (hi-only bf16, [S,H,D] cols)
    unsigned short* WqkvT = Obuf + NE;      // 3 * WN
    unsigned short* WoT = WqkvT + 3 * WN;   // WN
    float* ct = (float*)(WoT + WN);
    float* st = ct + (size_t)Sn * 32;

    convx_kernel<<<(int)(NE / 1024), 256, 0, stream>>>(x, Xh);
    tconv5_kernel<<<dim3(16, 16, 5), 256, 0, stream>>>(
        Wq, Wk, Wv, Wo, WqkvT, WoT, ct, st);

    gemm97<En, 1><<<dim3(3 * En / 128, Mn / 128), 256, 0, stream>>>(
        Xh, WqkvT, bq, bk, bv, Qb, Kb, VbT, nullptr, ct, st);

    attn_mfma_kernel<<<dim3(Sn / 128, Hn, Bn), 256, 0, stream>>>(
        Qb, Kb, VbT, mask, Obuf);

    gemm97<En, 0><<<dim3(En / 128, Mn / 128), 256, 0, stream>>>(
        Obuf, WoT, bo, nullptr, nullptr, nullptr, nullptr, nullptr,
        (float*)d_out, ct, st);
}

// Round 12
// 298.639 us; speedup vs baseline: 1.2573x; 1.0236x over previous
//
#include <hip/hip_runtime.h>
#include <hip/hip_bf16.h>
#include <math.h>

// Problem constants (fixed by the reference).
#define Bn 4
#define Sn 2048
#define En 1024
#define Hn 16
#define Dn 64
#define Mn (Bn * Sn)  // 8192 rows in the flattened GEMMs

typedef __attribute__((ext_vector_type(8))) short short8;
typedef __attribute__((ext_vector_type(4))) short short4v;
typedef __attribute__((ext_vector_type(4))) float f32x4;
typedef __attribute__((ext_vector_type(16))) float f32x16;
typedef __attribute__((ext_vector_type(2))) unsigned int uint2v;

#if __has_builtin(__builtin_amdgcn_exp2f)
#define EXP2(x) __builtin_amdgcn_exp2f(x)
#else
#define EXP2(x) exp2f(x)
#endif

#if __has_builtin(__builtin_amdgcn_permlane32_swap)
#define HAVE_PLSWAP 1
#endif

// async global->LDS, 16 B per lane; LDS dest = wave-uniform base + lane*16
#define GLOAD16(g, s) __builtin_amdgcn_global_load_lds( \
    (const __attribute__((address_space(1))) unsigned int*)(g), \
    (__attribute__((address_space(3))) unsigned int*)(s), 16, 0, 0)

__device__ inline unsigned short f2bf(float f) {  // round-to-nearest-even bf16
    unsigned int u = __float_as_uint(f);
    u += 0x7FFFu + ((u >> 16) & 1u);
    return (unsigned short)(u >> 16);
}
__device__ inline float bf2f(unsigned short h) {
    return __uint_as_float(((unsigned int)h) << 16);
}
__device__ inline short8 ld8s(const unsigned short* p) {  // LDS, 8B-aligned
    union { short4v h[2]; short8 v; } r;
    r.h[0] = *(const short4v*)p;
    r.h[1] = *(const short4v*)(p + 4);
    return r.v;
}
__device__ inline short8 g8(const unsigned short* p) {  // global, 16B-aligned
    union { int4 i; short8 v; } r;
    r.i = *(const int4*)p;
    return r.v;
}

// XOR-swizzled 64x64 bf16 LDS tile helpers (attn): row stride 128 B, byte
// offset XORed with (row&7)<<4. 16B-aligned -> single ds_*_b128 per access.
// (SQ_LDS_BANK_CONFLICT = exactly 4 per b128 read on this pattern --
// structural, scales exactly with read count across r2-r8.)
__device__ inline void st16(unsigned short* base, int row, int col16, int4 v) {
    const unsigned off = ((unsigned)(row * 128 + col16 * 2)) ^ ((unsigned)((row & 7) << 4));
    *(int4*)((char*)base + off) = v;
}
__device__ inline short8 ld16(const unsigned short* base, int row, int col16) {
    const unsigned off = ((unsigned)(row * 128 + col16 * 2)) ^ ((unsigned)((row & 7) << 4));
    union { int4 i; short8 v; } r;
    r.i = *(const int4*)((const char*)base + off);
    return r.v;
}

// ---------------------------------------------------------------------------
// Fused prep kernel, grid (16,16,37):
// z=0..2: Wq/Wk/Wv fp32 [K][N] -> transposed bf16 WqkvT + z*WN (rowLen 1024)
// z=3:    Wo -> WoT (rowLen 1024)
// z=4:    RoPE cos/sin table, fp64-accurate: [S][32] each
// z=5..36: X fp32 -> bf16 (hi only), 4 elts/thread (was convx_kernel;
//          chunk = (z-5)*256 + by*16 + bx covers NE/1024 = 8192 chunks).
// ---------------------------------------------------------------------------
__global__ __launch_bounds__(256) void prep_kernel(
    const float* __restrict__ X, unsigned short* __restrict__ Xh,
    const float* __restrict__ Wq, const float* __restrict__ Wk,
    const float* __restrict__ Wv, const float* __restrict__ Wo,
    unsigned short* __restrict__ WqkvT, unsigned short* __restrict__ WoT,
    float* __restrict__ ct, float* __restrict__ st) {
    const int m = blockIdx.z;
    const int t = threadIdx.x;
    if (m >= 5) {  // X fp32 -> bf16
        const int i = ((m - 5) * 256 + blockIdx.y * 16 + blockIdx.x) * 256 + t;
        float4 v = ((const float4*)X)[i];
        float f[4] = {v.x, v.y, v.z, v.w};
        short4v h;
#pragma unroll
        for (int j = 0; j < 4; ++j) h[j] = (short)f2bf(f[j]);
        ((short4v*)Xh)[i] = h;
        return;
    }
    if (m == 4) {  // RoPE table
        const int i = (blockIdx.y * 16 + blockIdx.x) * 256 + t;
        const int s = i >> 5, p = i & 31;
        double inv = pow(10000.0, -(double)p / 32.0);
        double a = (double)s * inv;
        ct[i] = (float)cos(a);
        st[i] = (float)sin(a);
        return;
    }
    const float* W = (m == 0) ? Wq : (m == 1) ? Wk : (m == 2) ? Wv : Wo;
    unsigned short* dst = (m < 3) ? WqkvT + (size_t)m * En * En : WoT;

    __shared__ float Ws[64][65];
    const int kb = blockIdx.y * 64, nb = blockIdx.x * 64;
    const int lr = t >> 2, lc = (t & 3) * 16;
#pragma unroll
    for (int u = 0; u < 4; ++u) {
        float4 v = *(const float4*)&W[(size_t)(kb + lr) * En + nb + lc + 4 * u];
        Ws[lr][lc + 4 * u + 0] = v.x; Ws[lr][lc + 4 * u + 1] = v.y;
        Ws[lr][lc + 4 * u + 2] = v.z; Ws[lr][lc + 4 * u + 3] = v.w;
    }
    __syncthreads();
    const int orow = t >> 2, ock = (t & 3) * 16;
#pragma unroll
    for (int u = 0; u < 4; ++u) {
        short4v hs;
#pragma unroll
        for (int j = 0; j < 4; ++j) hs[j] = (short)f2bf(Ws[ock + 4 * u + j][orow]);
        *(short4v*)&dst[(size_t)(nb + orow) * En + kb + ock + 4 * u] = hs;
    }
}

// ---------------------------------------------------------------------------
// m97-recipe MFMA GEMM (r11-verified: 305.7 µs config) + fused V-transpose
// epilogue. __launch_bounds__(256,4) pins VGPR <= 128 (r10: epilogue pushed
// VGPR to 132 -> m69 occupancy cliff -> 147.8 µs; r11 cap restored ~20%occ).
// C[M][N] = A[M][KN] . Bt[N][KN]^T. 128x128 tile, 4 waves, each 64x64 as
// 4x4 of 16x16x32 bf16 MFMA. global_load_lds width=16 into UNPADDED
// As/Bs[128][64]. Per K-iter: 8 gload + 16 ds_read_b128 + 32 MFMA/wave,
// 2 barriers. T1 XCD swizzle kept. C/D (16x16): col=lane&15, row=(l>>4)*4+r.
// Fused QKV epilogue; matrix by n0>>10:
//   mat 0/1 (Q/K): RoPE (+Q scale), bf16 out [B,H,S,D].
//   mat 2 (V): fused transpose -> VbT[B,H,D,S] via LDS T[128][136] (reuses
//     staging LDS after the K-loop; 136-short stride, <=2-way conflict).
// ---------------------------------------------------------------------------
template <int KN>
__global__ __launch_bounds__(256, 4) void gemm97(
    const unsigned short* __restrict__ A, const unsigned short* __restrict__ Bt,
    const float* __restrict__ b0, const float* __restrict__ bkv,
    const float* __restrict__ bvv,
    unsigned short* __restrict__ oQ, unsigned short* __restrict__ oK,
    unsigned short* __restrict__ oV,
    const float* __restrict__ ct, const float* __restrict__ st) {
    // 34816 B: As[128][64] | Bs[128][64] staging, reused as T[128][136] by
    // the V-transpose epilogue.
    __shared__ __align__(16) unsigned short shmem[17408];
    unsigned short (*As)[64] = (unsigned short(*)[64])&shmem[0];
    unsigned short (*Bs)[64] = (unsigned short(*)[64])&shmem[8192];
    const int t = threadIdx.x;
    const int w = t >> 6, l = t & 63;
    const int wm = w & 1, wn = w >> 1;
    const int q = l >> 4, ln16 = l & 15;  // quad, lane-in-16
    const int r8 = l >> 3, i8 = l & 7;    // staging: row-in-8, 16B chunk

    // T1: XCD-aware swizzle -- each XCD gets a contiguous chunk of work-ids.
    int bx = blockIdx.x, by = blockIdx.y;
    {
        const int gx = gridDim.x;
        const int nwg = gx * gridDim.y;
        if ((nwg & 7) == 0) {
            const int n = by * gx + bx;
            const int s = (n & 7) * (nwg >> 3) + (n >> 3);
            bx = s % gx; by = s / gx;
        }
    }
    const int m0 = by * 128, n0 = bx * 128;

    f32x4 acc[4][4];
#pragma unroll
    for (int i = 0; i < 4; ++i)
#pragma unroll
        for (int j = 0; j < 4; ++j)
#pragma unroll
            for (int r = 0; r < 4; ++r) acc[i][j][r] = 0.0f;

    // wave w stages rows 32w..32w+31 of both tiles; lane -> (8j+r8, 8*i8)
    const unsigned short* Ag = &A[(size_t)(m0 + 32 * w + r8) * KN + 8 * i8];
    const unsigned short* Bg = &Bt[(size_t)(n0 + 32 * w + r8) * KN + 8 * i8];

    for (int k0 = 0; k0 < KN; k0 += 64) {
        __syncthreads();  // prev iter's ds_reads done before overwrite
#pragma unroll
        for (int j = 0; j < 4; ++j) {
            GLOAD16(Ag + (size_t)(8 * j) * KN + k0, &As[32 * w + 8 * j][0]);
            GLOAD16(Bg + (size_t)(8 * j) * KN + k0, &Bs[32 * w + 8 * j][0]);
        }
        __syncthreads();  // compiler drains vmcnt before this barrier
#pragma unroll
        for (int ks = 0; ks < 2; ++ks) {
            short8 af[4], bf[4];
#pragma unroll
            for (int i = 0; i < 4; ++i)
                af[i] = ld8s(&As[64 * wm + 16 * i + ln16][32 * ks + 8 * q]);
#pragma unroll
            for (int j = 0; j < 4; ++j)
                bf[j] = ld8s(&Bs[64 * wn + 16 * j + ln16][32 * ks + 8 * q]);
#pragma unroll
            for (int i = 0; i < 4; ++i)
#pragma unroll
                for (int j = 0; j < 4; ++j)
                    acc[i][j] = __builtin_amdgcn_mfma_f32_16x16x32_bf16(
                        af[i], bf[j], acc[i][j], 0, 0, 0);
        }
    }

    const int mat = n0 >> 10;               // 0=Q, 1=K, 2=V (block-uniform)
    const int nIn0 = n0 & 1023;             // 128-aligned col in matrix
    if (mat == 2) {
        // ---- fused V transpose: acc -> T[d_local][s_local] -> VbT ----
        __syncthreads();  // all waves' K-loop ds_reads consumed
#pragma unroll
        for (int i = 0; i < 4; ++i)
#pragma unroll
            for (int j = 0; j < 4; ++j) {
                const int dl = 64 * wn + 16 * j + ln16;
                const float bv2 = bvv[nIn0 + dl];
#pragma unroll
                for (int r = 0; r < 4; ++r) {
                    const int sl = 64 * wm + 16 * i + 4 * q + r;
                    shmem[dl * 136 + sl] = f2bf(acc[i][j][r] + bv2);
                }
            }
        __syncthreads();
        // write-out: thread t owns d-row t>>1, s-half (t&1)*64 (128B)
        const int dr2 = t >> 1, sc2 = (t & 1) * 64;
        const int hh2 = (nIn0 >> 6) + (dr2 >> 6);
        unsigned short* vp =
            &oV[(((size_t)((m0 >> 11) * Hn + hh2)) * Dn + (dr2 & 63)) * Sn
                + (m0 & (Sn - 1)) + sc2];
        const unsigned short* tp = &shmem[dr2 * 136 + sc2];
#pragma unroll
        for (int u = 0; u < 8; ++u)
            *(int4*)(vp + 8 * u) = *(const int4*)(tp + 8 * u);
    } else {
        const int nIn = nIn0 + 64 * wn;     // 64-aligned col in matrix
        const int hh = nIn >> 6;            // head
        const float* bias = (mat == 0) ? b0 : bkv;
        unsigned short* op = (mat == 0) ? oQ : oK;
#pragma unroll
        for (int i = 0; i < 4; ++i)
#pragma unroll
            for (int r = 0; r < 4; ++r) {
                const int m = m0 + 64 * wm + 16 * i + 4 * q + r;
                const int b = m >> 11, s2 = m & (Sn - 1);
                const size_t base = (((size_t)(b * Hn + hh)) * Sn + s2) * Dn;
#pragma unroll
                for (int j = 0; j < 2; ++j) {  // RoPE pairs: tiles j, j+2
                    const int nh = 16 * j + ln16;  // 0..31 == freq idx
                    float v0 = acc[i][j][r] + bias[nIn + nh];
                    float v1 = acc[i][j + 2][r] + bias[nIn + nh + 32];
                    float c = ct[s2 * 32 + nh], sn = st[s2 * 32 + nh];
                    float o0 = v0 * c - v1 * sn;
                    float o1 = v1 * c + v0 * sn;
                    if (mat == 0) {
                        o0 *= 0.18033688011112042f;  // D^-0.5 * log2(e)
                        o1 *= 0.18033688011112042f;
                    }
                    op[base + nh] = f2bf(o0);
                    op[base + nh + 32] = f2bf(o1);
                }
            }
    }
}

// ---------------------------------------------------------------------------
// Output-projection GEMM, 64x128 tile / 2 waves (128 thr). Same verified
// 64x64 per-wave fragment body as gemm97 (wm=0; wn=w selects the N-half).
// WHY: at 128x128 the out grid is 512 blocks = 2 blocks/CU -- too few
// independent barrier groups for m97's implicit overlap (m114 needs 3-4).
// 64x128 -> grid 1024 = 4 blocks/CU resident (LDS 24KB -> 6, VGPR<=128 ->
// 4x64-thr-waves/SIMD), same 8 waves/CU but 4 independent blocks.
// Staging/wave: A rows 32w..32w+31 (4 gloads), B rows 64w..64w+63 (8).
// EPI: fp32 out [M][En] + bias.
// ---------------------------------------------------------------------------
__global__ __launch_bounds__(128, 4) void gemm64o(
    const unsigned short* __restrict__ A, const unsigned short* __restrict__ Bt,
    const float* __restrict__ b0, float* __restrict__ oF) {
    __shared__ unsigned short As[64][64];   // 8 KB
    __shared__ unsigned short Bs[128][64];  // 16 KB
    const int t = threadIdx.x;
    const int w = t >> 6, l = t & 63;       // 2 waves; wn = w
    const int q = l >> 4, ln16 = l & 15;
    const int r8 = l >> 3, i8 = l & 7;

    // T1: XCD-aware swizzle (grid 8x128 = 1024, %8 == 0).
    int bx = blockIdx.x, by = blockIdx.y;
    {
        const int gx = gridDim.x;
        const int nwg = gx * gridDim.y;
        const int n = by * gx + bx;
        const int s = (n & 7) * (nwg >> 3) + (n >> 3);
        bx = s % gx; by = s / gx;
    }
    const int m0 = by * 64, n0 = bx * 128;

    f32x4 acc[4][4];
#pragma unroll
    for (int i = 0; i < 4; ++i)
#pragma unroll
        for (int j = 0; j < 4; ++j)
#pragma unroll
            for (int r = 0; r < 4; ++r) acc[i][j][r] = 0.0f;

    const unsigned short* Ag = &A[(size_t)(m0 + 32 * w + r8) * En + 8 * i8];
    const unsigned short* Bg = &Bt[(size_t)(n0 + 64 * w + r8) * En + 8 * i8];

    for (int k0 = 0; k0 < En; k0 += 64) {
        __syncthreads();
#pragma unroll
        for (int j = 0; j < 4; ++j)
            GLOAD16(Ag + (size_t)(8 * j) * En + k0, &As[32 * w + 8 * j][0]);
#pragma unroll
        for (int j = 0; j < 8; ++j)
            GLOAD16(Bg + (size_t)(8 * j) * En + k0, &Bs[64 * w + 8 * j][0]);
        __syncthreads();
#pragma unroll
        for (int ks = 0; ks < 2; ++ks) {
            short8 af[4], bf[4];
#pragma unroll
            for (int i = 0; i < 4; ++i)
                af[i] = ld8s(&As[16 * i + ln16][32 * ks + 8 * q]);
#pragma unroll
            for (int j = 0; j < 4; ++j)
                bf[j] = ld8s(&Bs[64 * w + 16 * j + ln16][32 * ks + 8 * q]);
#pragma unroll
            for (int i = 0; i < 4; ++i)
#pragma unroll
                for (int j = 0; j < 4; ++j)
                    acc[i][j] = __builtin_amdgcn_mfma_f32_16x16x32_bf16(
                        af[i], bf[j], acc[i][j], 0, 0, 0);
        }
    }

#pragma unroll
    for (int i = 0; i < 4; ++i)
#pragma unroll
        for (int r = 0; r < 4; ++r) {
            const int m = m0 + 16 * i + 4 * q + r;
#pragma unroll
            for (int j = 0; j < 4; ++j) {
                const int n = n0 + 64 * w + 16 * j + ln16;
                oF[(size_t)m * En + n] = acc[i][j][r] + b0[n];
            }
        }
}

// ---------------------------------------------------------------------------
// Attn softmax helpers (round-3-verified formulation: truncate-to-bf16 pack,
// lsum accumulates the truncated values so numerator == denominator terms).
// ---------------------------------------------------------------------------
__device__ inline void softpack(const f32x16& accS, unsigned long long bm,
                                int c, int h2, float* lsum, unsigned* pw) {
#pragma unroll
    for (int g = 0; g < 4; ++g)
#pragma unroll
        for (int j = 0; j < 2; ++j) {
            const int r0 = 4 * g + 2 * j;
            float p0 = EXP2(accS[r0]);
            float p1 = EXP2(accS[r0 + 1]);
            if (bm) {  // wave-uniform; all-false mask skips this
                const int key = 32 * c + 8 * g + 4 * h2 + 2 * j;
                if ((bm >> key) & 1) p0 = 0.0f;
                if ((bm >> (key + 1)) & 1) p1 = 0.0f;
            }
            const unsigned u0 = __float_as_uint(p0) & 0xFFFF0000u;
            const unsigned u1 = __float_as_uint(p1) & 0xFFFF0000u;
            lsum[g] += __uint_as_float(u0);
            lsum[g] += __uint_as_float(u1);
            pw[2 * g + j] = (u0 >> 16) | u1;
        }
}

__device__ inline short8 pv_afrag(const unsigned* pw, int s, int h2) {
    union { unsigned u[4]; short8 v; } af;
#ifdef HAVE_PLSWAP
    uint2v r02 = __builtin_amdgcn_permlane32_swap(
        pw[4 * s + 0], pw[4 * s + 2], false, false);
    uint2v r13 = __builtin_amdgcn_permlane32_swap(
        pw[4 * s + 1], pw[4 * s + 3], false, false);
    af.u[0] = r02[0]; af.u[1] = r13[0];
    af.u[2] = r02[1]; af.u[3] = r13[1];
#else
    const unsigned x0 = pw[4 * s + 0], x1 = pw[4 * s + 1];
    const unsigned y0 = pw[4 * s + 2], y1 = pw[4 * s + 3];
    const unsigned py0 = (unsigned)__shfl_xor((int)y0, 32);
    const unsigned py1 = (unsigned)__shfl_xor((int)y1, 32);
    const unsigned px0 = (unsigned)__shfl_xor((int)x0, 32);
    const unsigned px1 = (unsigned)__shfl_xor((int)x1, 32);
    af.u[0] = h2 ? py0 : x0;
    af.u[1] = h2 ? py1 : x1;
    af.u[2] = h2 ? y0 : px0;
    af.u[3] = h2 ? y1 : px1;
#endif
    return af.v;
}

// ---------------------------------------------------------------------------
// MFMA flash attention, swapped-QK^T (round-7 configuration EXACT -- best
// measured: 116.5-118 µs, VGPR 128).
//   S^T = mfma(K, Q): per lane col = q = ln, rows = 16 keys.
//   P packed in-register (truncate-bf16) + v_permlane32_swap half-wave
//   exchange. KVBLK=64, 1 barrier per tile, XOR-swizzled K/V LDS tiles.
// O written HI-ONLY bf16 into Obuf[Mn][1024] ([S,H,D] cols; r7-verified:
// absmax unchanged at 2.44e-4).
// ---------------------------------------------------------------------------
__global__ __launch_bounds__(256) void attn_mfma_kernel(
    const unsigned short* __restrict__ Qb, const unsigned short* __restrict__ Kb,
    const unsigned short* __restrict__ VbT, const unsigned char* __restrict__ mask,
    unsigned short* __restrict__ Obuf) {
    __shared__ __align__(16) unsigned short Ks[2][64][64];  // [key][d], swizzled
    __shared__ __align__(16) unsigned short Vs[2][64][64];  // [d][key], swizzled

    const int t = threadIdx.x;
    const int w = t >> 6, l = t & 63, h2 = l >> 5, ln = l & 31;
    const int q0 = blockIdx.x * 128;
    const int h = blockIdx.y, b = blockIdx.z;
    const size_t ho = ((size_t)(b * Hn + h)) * Sn * Dn;
    const unsigned char* maskB = mask + (size_t)b * Sn;

    // Q fragment (B operand): lane holds Q[q0+32w+ln][16s+8h2 .. +7]
    short8 qh[4];
    const int qrow = q0 + 32 * w + ln;
#pragma unroll
    for (int s = 0; s < 4; ++s)
        qh[s] = g8(&Qb[ho + (size_t)qrow * Dn + 16 * s + 8 * h2]);

    f32x16 accO0, accO1;
#pragma unroll
    for (int i = 0; i < 16; ++i) { accO0[i] = 0.0f; accO1[i] = 0.0f; }
    float lsum[4] = {0.0f, 0.0f, 0.0f, 0.0f};  // partial P sums, q=ln

    // staging: thread t owns row t>>2 (key for K, d for V), 32 B at col (t&3)*16
    const int kr = t >> 2, kc = (t & 3) * 16;
    const unsigned short* Kp = &Kb[ho + (size_t)kr * Dn + kc];
    const unsigned short* Vp = &VbT[ho + (size_t)kr * Sn + kc];

    int4 ck0 = *(const int4*)Kp, ck1 = *(const int4*)(Kp + 8);
    int4 cv0 = *(const int4*)Vp, cv1 = *(const int4*)(Vp + 8);
    unsigned char cm = maskB[l];

#pragma unroll 2
    for (int kt = 0; kt < Sn / 64; ++kt) {
        const int pb = kt & 1;
        unsigned short* KsP = &Ks[pb][0][0];
        unsigned short* VsP = &Vs[pb][0][0];
        st16(KsP, kr, kc, ck0); st16(KsP, kr, kc + 8, ck1);
        st16(VsP, kr, kc, cv0); st16(VsP, kr, kc + 8, cv1);
        const unsigned long long bm = __ballot(cm != 0);  // keys kt*64 + 0..63
        __syncthreads();
        const int kn = ((kt + 1) & (Sn / 64 - 1)) * 64;  // prefetch (wraps)
        ck0 = *(const int4*)(Kp + (size_t)kn * Dn);
        ck1 = *(const int4*)(Kp + (size_t)kn * Dn + 8);
        cv0 = *(const int4*)(Vp + kn);
        cv1 = *(const int4*)(Vp + kn + 8);
        cm = maskB[kn + l];

#pragma unroll
        for (int c = 0; c < 2; ++c) {  // two 32-key subtiles
            // K fragment (A operand): lane holds K[32c+ln][16s+8h2 .. +7]
            short8 kf[4];
#pragma unroll
            for (int s = 0; s < 4; ++s)
                kf[s] = ld16(KsP, 32 * c + ln, 16 * s + 8 * h2);
            f32x16 accS;
#pragma unroll
            for (int i = 0; i < 16; ++i) accS[i] = 0.0f;
            __builtin_amdgcn_s_setprio(1);
#pragma unroll
            for (int s = 0; s < 4; ++s)  // S^T: col=q=ln, row=key
                accS = __builtin_amdgcn_mfma_f32_32x32x16_bf16(kf[s], qh[s], accS, 0, 0, 0);
            __builtin_amdgcn_s_setprio(0);

            unsigned pw[8];
            softpack(accS, bm, c, h2, lsum, pw);

#pragma unroll
            for (int s = 0; s < 2; ++s) {
                short8 af = pv_afrag(pw, s, h2);
                short8 vA = ld16(VsP, ln, 32 * c + 16 * s + 8 * h2);
                short8 vB = ld16(VsP, 32 + ln, 32 * c + 16 * s + 8 * h2);
                __builtin_amdgcn_s_setprio(1);
                accO0 = __builtin_amdgcn_mfma_f32_32x32x16_bf16(af, vA, accO0, 0, 0, 0);
                accO1 = __builtin_amdgcn_mfma_f32_32x32x16_bf16(af, vB, accO1, 0, 0, 0);
                __builtin_amdgcn_s_setprio(0);
            }
        }
    }

    // full row sum for q=ln: this lane's 16-key groups + partner half-wave's
    const float lme = (lsum[0] + lsum[1]) + (lsum[2] + lsum[3]);
    const float tot = lme + __shfl_xor(lme, 32);
    const float linv = 1.0f / fmaxf(tot, 1e-37f);
#pragma unroll
    for (int r = 0; r < 16; ++r) {
        const int row = (r & 3) + 8 * (r >> 2) + 4 * h2;  // q row of accO[r]
        const float lr = __shfl(linv, row);               // lane `row` holds it
        const int s = q0 + 32 * w + row;
        const size_t base = ((size_t)b * Sn + s) * 1024 + h * Dn;  // [M][1024]
        Obuf[base + ln] = f2bf(accO0[r] * lr);
        Obuf[base + 32 + ln] = f2bf(accO1[r] * lr);
    }
}

// ---------------------------------------------------------------------------
// Workspace (shorts unless noted):
//   Xh | Qb | Kb | VbT | Obuf(NE) | WqkvT(3*WN) | WoT(WN) | ct st
// ---------------------------------------------------------------------------
extern "C" void kernel_launch(void* const* d_in, const int* in_sizes, int n_in,
                              void* d_out, int out_size, void* d_ws, size_t ws_size,
                              hipStream_t stream) {
    const float* x  = (const float*)d_in[0];
    const float* Wq = (const float*)d_in[1];
    const float* bq = (const float*)d_in[2];
    const float* Wk = (const float*)d_in[3];
    const float* bk = (const float*)d_in[4];
    const float* Wv = (const float*)d_in[5];
    const float* bv = (const float*)d_in[6];
    const float* Wo = (const float*)d_in[7];
    const float* bo = (const float*)d_in[8];
    const unsigned char* mask = (const unsigned char*)d_in[9];

    const size_t NE = (size_t)Mn * En;  // 8,388,608
    const size_t WN = (size_t)En * En;  // 1,048,576
    unsigned short* ws = (unsigned short*)d_ws;
    unsigned short* Xh = ws;
    unsigned short* Qb = Xh + NE;
    unsigned short* Kb = Qb + NE;
    unsigned short* VbT = Kb + NE;
    unsigned short* Obuf = VbT + NE;        // NE (hi-only bf16, [S,H,D] cols)
    unsigned short* WqkvT = Obuf + NE;      // 3 * WN
    unsigned short* WoT = WqkvT + 3 * WN;   // WN
    float* ct = (float*)(WoT + WN);
    float* st = ct + (size_t)Sn * 32;

    prep_kernel<<<dim3(16, 16, 37), 256, 0, stream>>>(
        x, Xh, Wq, Wk, Wv, Wo, WqkvT, WoT, ct, st);

    gemm97<En><<<dim3(3 * En / 128, Mn / 128), 256, 0, stream>>>(
        Xh, WqkvT, bq, bk, bv, Qb, Kb, VbT, ct, st);

    attn_mfma_kernel<<<dim3(Sn / 128, Hn, Bn), 256, 0, stream>>>(
        Qb, Kb, VbT, mask, Obuf);

    gemm64o<<<dim3(En / 128, Mn / 64), 128, 0, stream>>>(
        Obuf, WoT, bo, (float*)d_out);
}